// Round 6
// baseline (1312.830 us; speedup 1.0000x reference)
//
#include <hip/hip_runtime.h>

// SocialPoolingLayer: fused edge-MLP (relu(pair@W1+b1)@W2+b2, sigmoid gate, elemwise
// product) + scatter-mean by src node.
// Round 15: bucket pipeline KEPT (3 dispatches), main-kernel memory regime RESTORED.
//  - R5 failure isolated: gathering f32 emb rows (256B, 12.8MB set) exploded L2-fill
//    to 1.45GB @ 3.2TB/s = 823us. R1's regime (bf16 emb_bf, 4-lanes-per-row staging,
//    src-ordered blocks) measured 30MB FETCH / 78us. That staging is now verbatim.
//  - ws fit via 4-src buckets with 16-BIT entries: dst u16 (N<65536) + 2-bit src key
//    in a packed word array (atomicOr at same cursor slot, skipped for key 0).
//    dst16 2.8MB + src2 0.35MB + bcur 50KB + emb_bf 6.4MB + wpack = 9.63MB < 10.03MB.
//  - Main: block = bucket (12500, src-ordered). 2-bit LDS counting sort -> exact src
//    grouping; LDS histogram == global node degree (node's edges live in ONE bucket)
//    -> no cnt array, no finalize dispatch. Flush = R1's ballot segment loop.
//  - Aux: prep (weights|bgp|emb->bf16|zero summed|zero bcur+src2) + bucket_scatter
//    (1 cursor atomic + u16 store + optional atomicOr per edge).

typedef unsigned short ushort_t;
typedef __attribute__((ext_vector_type(8))) short     bf16x8;   // 8 bf16 = 4 VGPRs
typedef __attribute__((ext_vector_type(8))) unsigned short u16x8;
typedef __attribute__((ext_vector_type(4))) float     f32x4;

constexpr int D        = 64;
constexpr int TILE     = 64;     // edges per block-tile (4 waves x 16 edges)
constexpr int BLOCK    = 256;
constexpr int NFRAG    = 32;     // 16 (W1) + 8 (W2) + 8 (W2@Wg) B-fragments
constexpr int SLAB_B   = 4352;   // per-wave slab: 16 rows x 272 B
constexpr int PAIR_STR = 136;    // pair row stride (bf16): 272 B
constexpr int H_STR    = 72;     // h row stride (bf16): 144 B
constexpr int CAP      = 112;    // bucket capacity; mean fill 64, max ~99 (E=800k)
constexpr int SRC2_W   = CAP / 16;   // 7 packed u32 words per bucket
constexpr float LOG2E  = 1.4426950408889634f;

static __device__ __forceinline__ ushort_t f2bf(float f) {
    union { float f; unsigned int u; } v; v.f = f;
    const unsigned int r = v.u + 0x7FFFu + ((v.u >> 16) & 1u);   // RNE
    return (ushort_t)(r >> 16);
}

static __device__ __forceinline__ float fexp2(float x) {
    float r; asm("v_exp_f32 %0, %1" : "=v"(r) : "v"(x)); return r;
}
static __device__ __forceinline__ float frcp(float x) {
    float r; asm("v_rcp_f32 %0, %1" : "=v"(r) : "v"(x)); return r;
}

// ---- prep: weight pack + W2Wg + bg' + emb->bf16 + zero summed + zero bcur/src2 ----
// Weight fragment layout (verified R3): frag f, lane l, elem j -> W[k][n],
// k = kc*32 + (l>>4)*8 + j, n = nt*16 + (l&15).
// f in [0,16): W1; [16,24): W2; [24,32): (W2@Wg)*log2e.

__global__ void prep_kernel(const float* __restrict__ W1, const float* __restrict__ W2,
                            const float* __restrict__ Wg,
                            const float* __restrict__ b2, const float* __restrict__ bg,
                            const float* __restrict__ emb,
                            ushort_t* __restrict__ wpack, float* __restrict__ bgp,
                            ushort_t* __restrict__ emb_bf, int* __restrict__ auxz,
                            float* __restrict__ summed,
                            int total_emb, int aux_ints, int cvt_blocks, int zblocks) {
    const int bid = blockIdx.x;
    if (bid < 64) {                              // 64*256 == NFRAG*512: weight packing
        const int t = bid * 256 + threadIdx.x;
        const int f = t >> 9;
        const int l = (t >> 3) & 63;
        const int j = t & 7;
        const int k = ((f < 16) ? (f & 3) : ((f - 16) & 1)) * 32 + (l >> 4) * 8 + j;
        const int n = ((f < 16) ? (f >> 2) : (((f & 7)) >> 1)) * 16 + (l & 15);
        float v;
        if (f < 16)      v = W1[k * 64 + n];
        else if (f < 24) v = W2[k * 64 + n];
        else {                                   // (W2@Wg)[k][n] * log2(e)
            float s = 0.f;
            const float* wr = W2 + k * 64;
#pragma unroll 8
            for (int m = 0; m < 64; ++m) s += wr[m] * Wg[m * 64 + n];
            v = s * LOG2E;
        }
        wpack[t] = f2bf(v);
    } else if (bid == 64) {                      // bg' = (b2@Wg + bg) * log2(e)
        const int n = threadIdx.x;
        if (n < 64) {
            float s = bg[n];
#pragma unroll 8
            for (int m = 0; m < 64; ++m) s += b2[m] * Wg[m * 64 + n];
            bgp[n] = s * LOG2E;
        }
    } else if (bid < 65 + cvt_blocks) {          // node_emb -> bf16
        const int idx  = (bid - 65) * 256 + threadIdx.x;
        const int base = idx * 8;
        if (base < total_emb) {
            const float4 a = *(const float4*)(emb + base);
            const float4 b = *(const float4*)(emb + base + 4);
            u16x8 p;
            p[0]=f2bf(a.x); p[1]=f2bf(a.y); p[2]=f2bf(a.z); p[3]=f2bf(a.w);
            p[4]=f2bf(b.x); p[5]=f2bf(b.y); p[6]=f2bf(b.z); p[7]=f2bf(b.w);
            *(u16x8*)(emb_bf + base) = p;
        }
    } else if (bid < 65 + cvt_blocks + zblocks) {    // zero summed
        const int idx  = (bid - 65 - cvt_blocks) * 256 + threadIdx.x;
        const int base = idx * 4;
        if (base < total_emb)
            *(float4*)(summed + base) = (float4){0.f, 0.f, 0.f, 0.f};
    } else {                                     // zero bcur + src2 (contiguous span)
        const int idx  = (bid - 65 - cvt_blocks - zblocks) * 256 + threadIdx.x;
        const int base = idx * 4;
        if (base + 3 < aux_ints)
            *(int4*)(auxz + base) = (int4){0, 0, 0, 0};
        else
            for (int k = base; k < aux_ints; ++k) auxz[k] = 0;
    }
}

// ---- bucket_scatter: edge -> bucket[src>>2]; dst16[slot]=dst, src2 |= key<<2slot ---

__global__ void bucket_scatter(const int* __restrict__ ei, int* __restrict__ bcur,
                               ushort_t* __restrict__ dst16, unsigned* __restrict__ src2,
                               int E) {
    const int e = (blockIdx.x * 256 + threadIdx.x) * 4;
    if (e + 3 < E) {
        const int4 s = *(const int4*)(ei + e);
        const int4 d = *(const int4*)(ei + E + e);
#pragma unroll
        for (int u = 0; u < 4; ++u) {
            const int sv = (u == 0) ? s.x : (u == 1) ? s.y : (u == 2) ? s.z : s.w;
            const int dv = (u == 0) ? d.x : (u == 1) ? d.y : (u == 2) ? d.z : d.w;
            const int b  = sv >> 2;
            const int p  = atomicAdd(&bcur[b], 1);
            if (p < CAP) {
                dst16[b * CAP + p] = (ushort_t)dv;
                const int key = sv & 3;
                if (key) atomicOr(&src2[b * SRC2_W + (p >> 4)],
                                  (unsigned)key << ((p & 15) * 2));
            }
        }
    } else {
        for (int k = e; k < E; ++k) {
            const int sv = ei[k], b = sv >> 2;
            const int p = atomicAdd(&bcur[b], 1);
            if (p < CAP) {
                dst16[b * CAP + p] = (ushort_t)ei[E + k];
                const int key = sv & 3;
                if (key) atomicOr(&src2[b * SRC2_W + (p >> 4)],
                                  (unsigned)key << ((p & 15) * 2));
            }
        }
    }
}

// ------------- main: per-bucket 2-bit LDS sort + MFMA MLP + segment flush ----------
// Block = bucket b (srcs 4b..4b+3), blocks sweep src space linearly (R1's order).
// hcnt[k] == global degree of node 4b+k -> rc from LDS; no cnt array, no finalize.
// Staging from emb_bf: VERBATIM R1 pattern (4 consecutive lanes cover one edge's
// 128B src + 128B dst bf16 rows). Wave-private slabs, barrier-free across tiles.

__global__ __launch_bounds__(BLOCK, 8)
void edge_mlp_mfma(const ushort_t* __restrict__ emb_bf,   // [N][64] bf16
                   const ushort_t* __restrict__ dst16,    // [nbuckets][CAP]
                   const unsigned* __restrict__ src2,     // [nbuckets][SRC2_W]
                   const int* __restrict__ bcur,
                   const ushort_t* __restrict__ wpack,    // 32 packed B-frags
                   const float* __restrict__ b1, const float* __restrict__ b2,
                   const float* __restrict__ bgp,         // (b2@Wg + bg) * log2e
                   float* __restrict__ summed)            // [N][D] pre-zeroed (out)
{
    __shared__ __align__(16) char slab[4][SLAB_B];   // 17408 B: per-wave pair then h
    __shared__ unsigned bls[CAP];                     // src-sorted (key<<16|dst)
    __shared__ int hcnt[4], hoff[4];

    const int bid = blockIdx.x;
    int fill = bcur[bid];
    fill = (fill > CAP) ? CAP : fill;
    if (fill == 0) return;

    const int tid = threadIdx.x;

    // ---- 2-bit LDS counting sort ----
    if (tid < 4) hcnt[tid] = 0;
    __syncthreads();
    int key = 0; unsigned dv = 0;
    const bool hasE = tid < fill;
    if (hasE) {
        dv  = dst16[bid * CAP + tid];
        key = (int)((src2[bid * SRC2_W + (tid >> 4)] >> ((tid & 15) * 2)) & 3u);
        atomicAdd(&hcnt[key], 1);
    }
    __syncthreads();
    if (tid == 0) {
        int s = 0;
#pragma unroll
        for (int k = 0; k < 4; ++k) { hoff[k] = s; s += hcnt[k]; }
    }
    __syncthreads();
    if (hasE) {
        const int p = atomicAdd(&hoff[key], 1);
        bls[p] = ((unsigned)key << 16) | dv;
    }
    __syncthreads();

    const int w    = tid >> 6;           // wave id: owns slab[w] + rows 16w..16w+15
    const int ln   = tid & 63;
    const int quad = ln >> 4;
    const int cn   = ln & 15;
    ushort_t* pairW = (ushort_t*)slab[w];   // [16][136]
    ushort_t* hW    = (ushort_t*)slab[w];   // [16][72] (overwrites pair after a1 reads)

    // hoisted biases (loop-invariant)
    float bb1[4], bb2[4], bbg[4];
#pragma unroll
    for (int nt = 0; nt < 4; ++nt) {
        bb1[nt] = b1 [nt * 16 + cn];
        bb2[nt] = b2 [nt * 16 + cn];
        bbg[nt] = bgp[nt * 16 + cn];
    }

    const int ntile = (fill + TILE - 1) / TILE;     // <= 2 at CAP=112
    for (int t = 0; t < ntile; ++t) {

        // ---- stage (VERBATIM R1): 4 lanes cover one edge's bf16 src+dst rows ----
        {
            const int e = tid >> 2, q4 = tid & 3;   // e: edge slot 0..63
            ushort_t* prow = (ushort_t*)&slab[e >> 4][(e & 15) * (PAIR_STR * 2)];
            const int idx = t * TILE + e;
            if (idx < fill) {
                const unsigned en = bls[idx];
                const int s = (bid << 2) | (int)((en >> 16) & 3);
                const int d = (int)(en & 0xFFFFu);
                const ushort_t* sr = emb_bf + (size_t)s * D + q4 * 16;
                const ushort_t* dr = emb_bf + (size_t)d * D + q4 * 16;
                *(u16x8*)&prow[q4 * 16]          = *(const u16x8*)sr;
                *(u16x8*)&prow[q4 * 16 + 8]      = *(const u16x8*)(sr + 8);
                *(u16x8*)&prow[64 + q4 * 16]     = *(const u16x8*)dr;
                *(u16x8*)&prow[64 + q4 * 16 + 8] = *(const u16x8*)(dr + 8);
            } else {
                const u16x8 z = {0,0,0,0,0,0,0,0};
                *(u16x8*)&prow[q4 * 16]          = z;
                *(u16x8*)&prow[q4 * 16 + 8]      = z;
                *(u16x8*)&prow[64 + q4 * 16]     = z;
                *(u16x8*)&prow[64 + q4 * 16 + 8] = z;
            }
        }

        // ---- GEMM1: h = relu(pair @ W1 + b1), M=16 K=128 N=64 (kc-outer) ----
        f32x4 acc1[4];
#pragma unroll
        for (int nt = 0; nt < 4; ++nt)
            acc1[nt] = (f32x4){bb1[nt], bb1[nt], bb1[nt], bb1[nt]};
#pragma unroll
        for (int kc = 0; kc < 4; ++kc) {
            const bf16x8 a = *(const bf16x8*)&pairW[cn * PAIR_STR + kc * 32 + quad * 8];
#pragma unroll
            for (int nt = 0; nt < 4; ++nt) {
                const bf16x8 bf = *(const bf16x8*)(wpack + ((nt * 4 + kc) * 64 + ln) * 8);
                acc1[nt] = __builtin_amdgcn_mfma_f32_16x16x32_bf16(a, bf, acc1[nt], 0, 0, 0);
            }
        }
#pragma unroll
        for (int nt = 0; nt < 4; ++nt)
#pragma unroll
            for (int r = 0; r < 4; ++r)
                hW[(quad * 4 + r) * H_STR + nt * 16 + cn] = f2bf(fmaxf(acc1[nt][r], 0.f));

        // ---- GEMM2+3 fused: interaction = h@W2+b2 ; gate_pre = h@(W2Wg*log2e)+bg' ----
        f32x4 acc2[4], accg[4];
#pragma unroll
        for (int nt = 0; nt < 4; ++nt) {
            acc2[nt] = (f32x4){bb2[nt], bb2[nt], bb2[nt], bb2[nt]};
            accg[nt] = (f32x4){bbg[nt], bbg[nt], bbg[nt], bbg[nt]};
        }
#pragma unroll
        for (int kc = 0; kc < 2; ++kc) {
            const bf16x8 a = *(const bf16x8*)&hW[cn * H_STR + kc * 32 + quad * 8];
#pragma unroll
            for (int nt = 0; nt < 4; ++nt) {
                const bf16x8 bf2 = *(const bf16x8*)(wpack + ((16 + nt * 2 + kc) * 64 + ln) * 8);
                const bf16x8 bfg = *(const bf16x8*)(wpack + ((24 + nt * 2 + kc) * 64 + ln) * 8);
                acc2[nt] = __builtin_amdgcn_mfma_f32_16x16x32_bf16(a, bf2, acc2[nt], 0, 0, 0);
                accg[nt] = __builtin_amdgcn_mfma_f32_16x16x32_bf16(a, bfg, accg[nt], 0, 0, 0);
            }
        }

        // ---- gated = interaction * sigmoid(gate_pre) -> per-lane PREFIX sums ----
        float P[4][4];
#pragma unroll
        for (int nt = 0; nt < 4; ++nt) {
#pragma unroll
            for (int r = 0; r < 4; ++r) {
                const float ex = fexp2(-accg[nt][r]);
                P[nt][r] = acc2[nt][r] * frcp(1.0f + ex);
            }
            P[nt][1] += P[nt][0];
            P[nt][2] += P[nt][1];
            P[nt][3] += P[nt][2];
        }

        // ---- segmented flush: ballot boundary mask + scalar segment loop ----
        {
            const int idxr = t * TILE + 16 * w + (ln & 15);
            int mySrc = -1;
            if (idxr < fill)
                mySrc = (bid << 2) | (int)((bls[idxr] >> 16) & 3);
            const int prevLane = (ln & 48) | ((ln + 15) & 15);
            const int prevSrc  = __shfl(mySrc, prevLane);   // wraps; bit0 forced below
            unsigned bmask = ((unsigned)__ballot(mySrc != prevSrc) & 0xFFFFu) | 1u;
            const int q4r = 4 * quad;
            while (bmask) {
                const int a = __builtin_ctz(bmask);
                bmask &= (bmask - 1u);
                const int b = bmask ? __builtin_ctz(bmask) : 16;
                const int sseg = __builtin_amdgcn_readlane(mySrc, a);
                if (sseg >= 0) {
                    const int lo  = a - q4r, hi = b - q4r;
                    const int clo = lo < 0 ? 0 : (lo > 4 ? 4 : lo);
                    const int chi = hi < 0 ? 0 : (hi > 4 ? 4 : hi);
                    const bool ge1 = chi > 1, ge2 = chi > 2, ge3 = chi > 3;
                    const bool l0 = clo > 0, l1 = clo > 1, l2 = clo > 2;
                    const bool valid = chi > clo;
                    float tt[4];
#pragma unroll
                    for (int nt = 0; nt < 4; ++nt) {
                        const float sh = ge2 ? (ge3 ? P[nt][3] : P[nt][2])
                                             : (ge1 ? P[nt][1] : P[nt][0]);
                        const float sl = l1 ? (l2 ? P[nt][2] : P[nt][1])
                                            : (l0 ? P[nt][0] : 0.f);
                        tt[nt] = valid ? sh - sl : 0.f;
                    }
                    tt[0] += __shfl_xor(tt[0], 16); tt[0] += __shfl_xor(tt[0], 32);
                    tt[1] += __shfl_xor(tt[1], 16); tt[1] += __shfl_xor(tt[1], 32);
                    tt[2] += __shfl_xor(tt[2], 16); tt[2] += __shfl_xor(tt[2], 32);
                    tt[3] += __shfl_xor(tt[3], 16); tt[3] += __shfl_xor(tt[3], 32);
                    const float tot = (quad < 2) ? (quad == 0 ? tt[0] : tt[1])
                                                 : (quad == 2 ? tt[2] : tt[3]);
                    const float rc = frcp(fmaxf((float)hcnt[sseg & 3], 1.0f));
                    unsafeAtomicAdd(&summed[(size_t)sseg * D + ln], tot * rc);
                }
            }
        }
    }
}

extern "C" void kernel_launch(void* const* d_in, const int* in_sizes, int n_in,
                              void* d_out, int out_size, void* d_ws, size_t ws_size,
                              hipStream_t stream) {
    const float* node_emb   = (const float*)d_in[0];
    const int*   edge_index = (const int*)d_in[1];
    const float* W1 = (const float*)d_in[2];
    const float* b1 = (const float*)d_in[3];
    const float* W2 = (const float*)d_in[4];
    const float* b2 = (const float*)d_in[5];
    const float* Wg = (const float*)d_in[6];
    const float* bg = (const float*)d_in[7];

    const int N = in_sizes[0] / D;
    const int E = in_sizes[1] / 2;
    const int total_emb = N * D;
    const int nbuckets  = (N + 3) >> 2;                 // 12500 for N=50000

    // ws layout (9.63 MB < 10.03 MB proven extent), 16B-aligned segments:
    // bcur[nbuckets pad16] | src2[nbuckets*7 pad16] | dst16[nbuckets*CAP u16]
    // | bgp[64 f32] | wpack[16K bf16] | emb_bf[N*64 bf16]
    const int bcur_ints = (nbuckets + 3) & ~3;                    // 12500 -> 12500 pad
    const int src2_ints = ((nbuckets * SRC2_W) + 3) & ~3;         // 87500 -> 87500 pad
    int* bcur        = (int*)d_ws;
    unsigned* src2   = (unsigned*)(bcur + bcur_ints);
    ushort_t* dst16  = (ushort_t*)(src2 + src2_ints);
    float* bgp       = (float*)(dst16 + (size_t)nbuckets * CAP);
    ushort_t* wpack  = (ushort_t*)(bgp + 64);
    ushort_t* emb_bf = wpack + NFRAG * 512;

    float* summed = (float*)d_out;

    const int aux_ints   = bcur_ints + src2_ints;       // zeroed as one span
    const int cvt_blocks = (total_emb / 8 + 255) / 256;
    const int zblocks    = (total_emb / 4 + 255) / 256;
    const int azblocks   = ((aux_ints + 3) / 4 + 255) / 256;
    prep_kernel<<<65 + cvt_blocks + zblocks + azblocks, 256, 0, stream>>>(
        W1, W2, Wg, b2, bg, node_emb,
        wpack, bgp, emb_bf, bcur, summed, total_emb, aux_ints, cvt_blocks, zblocks);

    const int e4blocks = ((E + 3) / 4 + 255) / 256;
    bucket_scatter<<<e4blocks, 256, 0, stream>>>(edge_index, bcur, dst16, src2, E);

    edge_mlp_mfma<<<nbuckets, BLOCK, 0, stream>>>(emb_bf, dst16, src2, bcur, wpack,
                                                  b1, b2, bgp, summed);
}

// Round 7
// 249.757 us; speedup vs baseline: 5.2564x; 5.2564x over previous
//
#include <hip/hip_runtime.h>

// SocialPoolingLayer: fused edge-MLP (relu(pair@W1+b1)@W2+b2, sigmoid gate, elemwise
// product) + scatter-mean by src node.
// Round 16: FULL REVERT to the proven R10/R1 pipeline (237.45us, main 78.2us).
// Post-mortems of R11-R15: every structural deviation from this configuration hit a
// hardware wall --
//   R11 coop grid.sync: cross-XCD L2 flush, 746us aux;
//   R13 per-edge atomics: L2 f32-atomic op ceiling (242G/s), main 211us;
//   R12/R14/R15 persistent/bucketed staging: L2 gather thrash, FETCH 30MB -> 0.4-1.6GB.
// The dense sorted-tile staging + barrier-free 4-wave MFMA kernel is a narrow memory-
// system sweet spot; it stays verbatim. ONE zero-risk addition vs R1: s_setprio(1)/(0)
// around the MFMA clusters (T5) -- this kernel is barrier-free with waves at different
// phases (stage/MFMA/flush), the exact regime where setprio measured +4-7% (m191),
// unlike barrier-lockstep GEMMs where it's null (m190). Worst case ~0.

typedef unsigned short ushort_t;
typedef __attribute__((ext_vector_type(8))) short     bf16x8;   // 8 bf16 = 4 VGPRs
typedef __attribute__((ext_vector_type(8))) unsigned short u16x8;
typedef __attribute__((ext_vector_type(4))) float     f32x4;

constexpr int D        = 64;
constexpr int TILE     = 64;     // edges per block (4 waves x 16 edges)
constexpr int BLOCK    = 256;
constexpr int NFRAG    = 32;     // 16 (W1) + 8 (W2) + 8 (W2@Wg) B-fragments
constexpr int SLAB_B   = 4352;   // per-wave slab: 16 rows x 272 B
constexpr int PAIR_STR = 136;    // pair row stride (bf16): 272 B
constexpr int H_STR    = 72;     // h row stride (bf16): 144 B
constexpr float LOG2E  = 1.4426950408889634f;

static __device__ __forceinline__ ushort_t f2bf(float f) {
    union { float f; unsigned int u; } v; v.f = f;
    const unsigned int r = v.u + 0x7FFFu + ((v.u >> 16) & 1u);   // RNE
    return (ushort_t)(r >> 16);
}

static __device__ __forceinline__ float fexp2(float x) {
    float r; asm("v_exp_f32 %0, %1" : "=v"(r) : "v"(x)); return r;
}
static __device__ __forceinline__ float frcp(float x) {
    float r; asm("v_rcp_f32 %0, %1" : "=v"(r) : "v"(x)); return r;
}

// ---- prep: pack + W2Wg + bg' + emb->bf16 + histogram + summed-zero, one dispatch ----
// Weight fragment layout (verified R3): frag f, lane l, elem j -> W[k][n],
// k = kc*32 + (l>>4)*8 + j, n = nt*16 + (l&15).
// f in [0,16): W1; [16,24): W2; [24,32): (W2@Wg)*log2e.

__global__ void prep_kernel(const float* __restrict__ W1, const float* __restrict__ W2,
                            const float* __restrict__ Wg,
                            const float* __restrict__ b2, const float* __restrict__ bg,
                            const float* __restrict__ emb, const int* __restrict__ ei,
                            ushort_t* __restrict__ wpack, float* __restrict__ bgp,
                            ushort_t* __restrict__ emb_bf, int* __restrict__ cnt,
                            float* __restrict__ summed,
                            int total_emb, int cvt_blocks, int e4blocks, int E) {
    const int bid = blockIdx.x;
    if (bid < 64) {                              // 64*256 == NFRAG*512: weight packing
        const int t = bid * 256 + threadIdx.x;
        const int f = t >> 9;
        const int l = (t >> 3) & 63;
        const int j = t & 7;
        const int k = ((f < 16) ? (f & 3) : ((f - 16) & 1)) * 32 + (l >> 4) * 8 + j;
        const int n = ((f < 16) ? (f >> 2) : (((f & 7)) >> 1)) * 16 + (l & 15);
        float v;
        if (f < 16)      v = W1[k * 64 + n];
        else if (f < 24) v = W2[k * 64 + n];
        else {                                   // (W2@Wg)[k][n] * log2(e)
            float s = 0.f;
            const float* wr = W2 + k * 64;
#pragma unroll 8
            for (int m = 0; m < 64; ++m) s += wr[m] * Wg[m * 64 + n];
            v = s * LOG2E;
        }
        wpack[t] = f2bf(v);
    } else if (bid < 64 + cvt_blocks) {          // node_emb -> bf16
        const int idx  = (bid - 64) * 256 + threadIdx.x;
        const int base = idx * 8;
        if (base < total_emb) {
            const float4 a = *(const float4*)(emb + base);
            const float4 b = *(const float4*)(emb + base + 4);
            u16x8 p;
            p[0]=f2bf(a.x); p[1]=f2bf(a.y); p[2]=f2bf(a.z); p[3]=f2bf(a.w);
            p[4]=f2bf(b.x); p[5]=f2bf(b.y); p[6]=f2bf(b.z); p[7]=f2bf(b.w);
            *(u16x8*)(emb_bf + base) = p;
        }
    } else if (bid == 64 + cvt_blocks) {         // bg' = (b2@Wg + bg) * log2(e)  (fp32)
        const int n = threadIdx.x;
        if (n < 64) {
            float s = bg[n];
#pragma unroll 8
            for (int m = 0; m < 64; ++m) s += b2[m] * Wg[m * 64 + n];
            bgp[n] = s * LOG2E;
        }
    } else if (bid < 65 + cvt_blocks + e4blocks) {   // edge histogram by src
        const int e = ((bid - 65 - cvt_blocks) * 256 + threadIdx.x) * 4;
        if (e + 3 < E) {
            const int4 v = *(const int4*)(ei + e);
            atomicAdd(&cnt[v.x], 1); atomicAdd(&cnt[v.y], 1);
            atomicAdd(&cnt[v.z], 1); atomicAdd(&cnt[v.w], 1);
        } else {
            for (int k = e; k < E; ++k) atomicAdd(&cnt[ei[k]], 1);
        }
    } else {                                     // zero summed (consumed 2 nodes later)
        const int idx  = (bid - 65 - cvt_blocks - e4blocks) * 256 + threadIdx.x;
        const int base = idx * 4;
        if (base < total_emb)
            *(float4*)(summed + base) = (float4){0.f, 0.f, 0.f, 0.f};
    }
}

// ---------------- scan: per-block exclusive offsets + block sums ----------

__global__ void scan_block(const int* __restrict__ cnt, int* __restrict__ off,
                           int* __restrict__ bsum, int N) {
    __shared__ int s[256];
    const int t = threadIdx.x, i = blockIdx.x * 256 + t;
    const int x = (i < N) ? cnt[i] : 0;
    s[t] = x; __syncthreads();
    for (int d = 1; d < 256; d <<= 1) {
        const int v = (t >= d) ? s[t - d] : 0;
        __syncthreads();
        s[t] += v;
        __syncthreads();
    }
    if (i < N) off[i] = s[t] - x;                 // block-local exclusive prefix
    if (t == 255) bsum[blockIdx.x] = s[255];
}

// scatter with inline bsum prefix (nb <= 256); off[] doubles as insertion cursor.
// Writes packed (src<<16)|dst per slot -- requires N < 65536.
__global__ void scatter_idx(const int* __restrict__ ei, int* __restrict__ off,
                            const int* __restrict__ bsum, unsigned* __restrict__ sorted,
                            int E, int nb) {
    __shared__ int pref[256];
    const int t = threadIdx.x;
    const int x = (t < nb) ? bsum[t] : 0;
    pref[t] = x; __syncthreads();
    for (int d = 1; d < 256; d <<= 1) {
        const int v = (t >= d) ? pref[t - d] : 0;
        __syncthreads();
        pref[t] += v;
        __syncthreads();
    }
    // pref[] inclusive prefix of bsum; exclusive for block b is pref[b-1] (0 if b==0)
    const int e = (blockIdx.x * blockDim.x + t) * 4;
    if (e + 3 < E) {
        const int4 v = *(const int4*)(ei + e);        // src
        const int4 d = *(const int4*)(ei + E + e);    // dst
        const int bx = v.x >> 8, by = v.y >> 8, bz = v.z >> 8, bw = v.w >> 8;
        sorted[(bx ? pref[bx - 1] : 0) + atomicAdd(&off[v.x], 1)] =
            ((unsigned)v.x << 16) | (unsigned)d.x;
        sorted[(by ? pref[by - 1] : 0) + atomicAdd(&off[v.y], 1)] =
            ((unsigned)v.y << 16) | (unsigned)d.y;
        sorted[(bz ? pref[bz - 1] : 0) + atomicAdd(&off[v.z], 1)] =
            ((unsigned)v.z << 16) | (unsigned)d.z;
        sorted[(bw ? pref[bw - 1] : 0) + atomicAdd(&off[v.w], 1)] =
            ((unsigned)v.w << 16) | (unsigned)d.w;
    } else {
        for (int k = e; k < E; ++k) {
            const int s = ei[k], b = s >> 8;
            sorted[(b ? pref[b - 1] : 0) + atomicAdd(&off[s], 1)] =
                ((unsigned)s << 16) | (unsigned)ei[E + k];
        }
    }
}

// ---------------- fused MFMA MLP + register segmented scatter (barrier-free) --------
// Wave w exclusively owns its 4352B slab + srcIds/rcS rows 16w..16w+15. All LDS
// dependencies are intra-wave (issue-order DS pipe + compiler lgkmcnt waits), so
// pair -> h reuse one slab with no __syncthreads. Gated values never touch LDS:
// segmented reduction via per-lane prefix sums + ballot boundary mask + scalar
// segment loop; cross-quad butterfly only at flush. setprio(1) brackets the MFMA
// clusters (T5: waves here are at different phases, scheduler has room to arbitrate).

__global__ __launch_bounds__(BLOCK, 8)
void edge_mlp_mfma(const ushort_t* __restrict__ emb_bf,   // [N][64] bf16
                   const unsigned* __restrict__ sorted,   // packed (src<<16)|dst, sorted
                   const ushort_t* __restrict__ wpack,    // 32 packed B-frags
                   const float* __restrict__ b1, const float* __restrict__ b2,
                   const float* __restrict__ bgp,         // (b2@Wg + bg) * log2e
                   const int*   __restrict__ cnt,         // per-node edge counts
                   float* __restrict__ summed,            // [N][D] pre-zeroed
                   int E)
{
    __shared__ char  slab[4][SLAB_B];    // 17408 B: per-wave pair then h
    __shared__ int   srcIds[TILE];
    __shared__ float rcS[TILE];

    const int tid = threadIdx.x;

    // ---- stage: one packed 4B load -> two 128B row gathers into per-wave slab ----
    {
        const int e = tid >> 2, q4 = tid & 3;     // e: edge slot 0..63, q4: 16-elem quarter
        ushort_t* prow = (ushort_t*)&slab[e >> 4][(e & 15) * (PAIR_STR * 2)];
        const int ide = blockIdx.x * TILE + e;
        if (ide < E) {
            const unsigned p = sorted[ide];
            const int s  = (int)(p >> 16);
            const int dn = (int)(p & 0xFFFFu);
            if (q4 == 0) { srcIds[e] = s; rcS[e] = frcp(fmaxf((float)cnt[s], 1.0f)); }
            const ushort_t* sr = emb_bf + (size_t)s  * D + q4 * 16;
            const ushort_t* dr = emb_bf + (size_t)dn * D + q4 * 16;
            *(u16x8*)&prow[q4 * 16]          = *(const u16x8*)sr;
            *(u16x8*)&prow[q4 * 16 + 8]      = *(const u16x8*)(sr + 8);
            *(u16x8*)&prow[64 + q4 * 16]     = *(const u16x8*)dr;
            *(u16x8*)&prow[64 + q4 * 16 + 8] = *(const u16x8*)(dr + 8);
        } else {
            if (q4 == 0) { srcIds[e] = -1; rcS[e] = 1.0f; }
            const u16x8 z = {0,0,0,0,0,0,0,0};
            *(u16x8*)&prow[q4 * 16]          = z;
            *(u16x8*)&prow[q4 * 16 + 8]      = z;
            *(u16x8*)&prow[64 + q4 * 16]     = z;
            *(u16x8*)&prow[64 + q4 * 16 + 8] = z;
        }
    }

    const int w    = tid >> 6;           // wave id: owns slab[w] + rows 16w..16w+15
    const int ln   = tid & 63;
    const int quad = ln >> 4;
    const int cn   = ln & 15;
    ushort_t* pairW = (ushort_t*)slab[w];   // [16][136]
    ushort_t* hW    = (ushort_t*)slab[w];   // [16][72]  (overwrites pair after a1 reads)

    // ---- GEMM1: h = relu(pair @ W1 + b1), M=16 K=128 N=64 (kc-outer) ----
    f32x4 acc1[4];
#pragma unroll
    for (int nt = 0; nt < 4; ++nt) {
        const float b = b1[nt * 16 + cn];
        acc1[nt] = (f32x4){b, b, b, b};
    }
    __builtin_amdgcn_s_setprio(1);
#pragma unroll
    for (int kc = 0; kc < 4; ++kc) {
        const bf16x8 a = *(const bf16x8*)&pairW[cn * PAIR_STR + kc * 32 + quad * 8];
#pragma unroll
        for (int nt = 0; nt < 4; ++nt) {
            const bf16x8 bf = *(const bf16x8*)(wpack + ((nt * 4 + kc) * 64 + ln) * 8);
            acc1[nt] = __builtin_amdgcn_mfma_f32_16x16x32_bf16(a, bf, acc1[nt], 0, 0, 0);
        }
    }
    __builtin_amdgcn_s_setprio(0);
#pragma unroll
    for (int nt = 0; nt < 4; ++nt)
#pragma unroll
        for (int r = 0; r < 4; ++r)
            hW[(quad * 4 + r) * H_STR + nt * 16 + cn] = f2bf(fmaxf(acc1[nt][r], 0.f));

    // ---- GEMM2+3 fused (kc-outer): interaction = h@W2+b2 ; gate_pre = h@(W2Wg*log2e)+bg' ----
    f32x4 acc2[4], accg[4];
#pragma unroll
    for (int nt = 0; nt < 4; ++nt) {
        const float b  = b2 [nt * 16 + cn];
        const float bG = bgp[nt * 16 + cn];
        acc2[nt] = (f32x4){b, b, b, b};
        accg[nt] = (f32x4){bG, bG, bG, bG};
    }
    __builtin_amdgcn_s_setprio(1);
#pragma unroll
    for (int kc = 0; kc < 2; ++kc) {
        const bf16x8 a = *(const bf16x8*)&hW[cn * H_STR + kc * 32 + quad * 8];
#pragma unroll
        for (int nt = 0; nt < 4; ++nt) {
            const bf16x8 bf2 = *(const bf16x8*)(wpack + ((16 + nt * 2 + kc) * 64 + ln) * 8);
            const bf16x8 bfg = *(const bf16x8*)(wpack + ((24 + nt * 2 + kc) * 64 + ln) * 8);
            acc2[nt] = __builtin_amdgcn_mfma_f32_16x16x32_bf16(a, bf2, acc2[nt], 0, 0, 0);
            accg[nt] = __builtin_amdgcn_mfma_f32_16x16x32_bf16(a, bfg, accg[nt], 0, 0, 0);
        }
    }
    __builtin_amdgcn_s_setprio(0);

    // ---- gated = interaction * sigmoid(gate_pre), folded into per-lane PREFIX sums ----
    // accg is pre-scaled by log2(e): sigmoid(x) = rcp(1 + 2^-x_hat). rcp/exp2 approx
    // (~1e-7 rel) is far below bf16 noise. P[nt][r] = sum of gated rows 4q..4q+r.
    float P[4][4];
#pragma unroll
    for (int nt = 0; nt < 4; ++nt) {
#pragma unroll
        for (int r = 0; r < 4; ++r) {
            const float ex = fexp2(-accg[nt][r]);
            P[nt][r] = acc2[nt][r] * frcp(1.0f + ex);
        }
        P[nt][1] += P[nt][0];
        P[nt][2] += P[nt][1];
        P[nt][3] += P[nt][2];
    }

    // ---- segmented scatter: ballot boundary mask + scalar segment loop ----
    {
        const int   rbase  = 16 * w;
        const int   myRow  = ln & 15;
        const int   mySrc  = srcIds[rbase + myRow];
        const float myRc   = rcS[rbase + myRow];
        const int   prevSrc = srcIds[rbase + ((myRow + 15) & 15)];   // wraps; bit0 forced
        unsigned bmask = ((unsigned)__ballot(mySrc != prevSrc) & 0xFFFFu) | 1u;
        const int q4r = 4 * quad;
        while (bmask) {
            const int a = __builtin_ctz(bmask);
            bmask &= (bmask - 1u);
            const int b = bmask ? __builtin_ctz(bmask) : 16;
            const int sseg = __builtin_amdgcn_readlane(mySrc, a);
            if (sseg >= 0) {
                // lane's row range for this segment: [a,b) ∩ [4q,4q+4), as prefix diff
                const int lo  = a - q4r, hi = b - q4r;
                const int clo = lo < 0 ? 0 : (lo > 4 ? 4 : lo);
                const int chi = hi < 0 ? 0 : (hi > 4 ? 4 : hi);
                const bool ge1 = chi > 1, ge2 = chi > 2, ge3 = chi > 3;
                const bool l0 = clo > 0, l1 = clo > 1, l2 = clo > 2;
                const bool valid = chi > clo;
                float t[4];
#pragma unroll
                for (int nt = 0; nt < 4; ++nt) {
                    const float sh = ge2 ? (ge3 ? P[nt][3] : P[nt][2])
                                         : (ge1 ? P[nt][1] : P[nt][0]);
                    const float sl = l1 ? (l2 ? P[nt][2] : P[nt][1])
                                        : (l0 ? P[nt][0] : 0.f);
                    t[nt] = valid ? sh - sl : 0.f;
                }
                t[0] += __shfl_xor(t[0], 16); t[0] += __shfl_xor(t[0], 32);
                t[1] += __shfl_xor(t[1], 16); t[1] += __shfl_xor(t[1], 32);
                t[2] += __shfl_xor(t[2], 16); t[2] += __shfl_xor(t[2], 32);
                t[3] += __shfl_xor(t[3], 16); t[3] += __shfl_xor(t[3], 32);
                const float tot = (quad < 2) ? (quad == 0 ? t[0] : t[1])
                                             : (quad == 2 ? t[2] : t[3]);
                const float rc = __uint_as_float(
                    __builtin_amdgcn_readlane(__float_as_uint(myRc), a));
                unsafeAtomicAdd(&summed[(size_t)sseg * D + ln], tot * rc);
            }
        }
    }
}

extern "C" void kernel_launch(void* const* d_in, const int* in_sizes, int n_in,
                              void* d_out, int out_size, void* d_ws, size_t ws_size,
                              hipStream_t stream) {
    const float* node_emb   = (const float*)d_in[0];
    const int*   edge_index = (const int*)d_in[1];
    const float* W1 = (const float*)d_in[2];
    const float* b1 = (const float*)d_in[3];
    const float* W2 = (const float*)d_in[4];
    const float* b2 = (const float*)d_in[5];
    const float* Wg = (const float*)d_in[6];
    const float* bg = (const float*)d_in[7];

    const int N = in_sizes[0] / D;
    const int E = in_sizes[1] / 2;
    const int total_emb = N * D;

    // ws layout == R5..R10's proven extent (10,034,048 B for N=50000, E=800000):
    // cnt[N] | off[N] | bsum[256] | sorted[E u32] | bgp[64 f32] | wpack[16K bf16] | emb_bf
    int* cnt    = (int*)d_ws;
    int* off    = cnt + N;
    int* bsum   = off + N;
    unsigned* sorted = (unsigned*)(bsum + 256);
    float* bgp  = (float*)(sorted + E);
    ushort_t* wpack  = (ushort_t*)(bgp + 64);
    ushort_t* emb_bf = wpack + NFRAG * 512;

    float* summed = (float*)d_out;

    hipMemsetAsync(cnt, 0, sizeof(int) * (size_t)N, stream);   // must precede prep's hist

    const int cvt_blocks = (total_emb / 8 + 255) / 256;
    const int e4blocks   = ((E + 3) / 4 + 255) / 256;
    const int zblocks    = (total_emb / 4 + 255) / 256;
    prep_kernel<<<64 + cvt_blocks + 1 + e4blocks + zblocks, 256, 0, stream>>>(
        W1, W2, Wg, b2, bg, node_emb, edge_index,
        wpack, bgp, emb_bf, cnt, summed, total_emb, cvt_blocks, e4blocks, E);

    const int nblocks = (N + 255) / 256;   // 196 (must be <= 256 for inline prefix)
    scan_block <<<nblocks, 256, 0, stream>>>(cnt, off, bsum, N);
    scatter_idx<<<e4blocks, 256, 0, stream>>>(edge_index, off, bsum, sorted, E, nblocks);

    const int ntiles = (E + TILE - 1) / TILE;
    edge_mlp_mfma<<<ntiles, BLOCK, 0, stream>>>(emb_bf, sorted, wpack,
                                                b1, b2, bgp, cnt, summed, E);
}

// Round 8
// 242.102 us; speedup vs baseline: 5.4226x; 1.0316x over previous
//
#include <hip/hip_runtime.h>

// SocialPoolingLayer: fused edge-MLP (relu(pair@W1+b1)@W2+b2, sigmoid gate, elemwise
// product) + scatter-mean by src node.
// Round 17: R16's setprio REMOVED (measured -19% on main: prio-1 MFMA waves starve
// co-resident waves' staging-gather issue -- this kernel's waves cycle through
// stage/MFMA/flush phases, so the TLP that hides gather latency got serialized).
// Pipeline = proven R10/R1 5-dispatch chain, main kernel = R1 verbatim EXCEPT:
//   h-store conversion now uses v_cvt_pk_bf16_f32 (inline asm, no builtin on gfx950).
//   Audit: the f2bf RNE bit-twiddle was ~4-5 VALU x 64 elems ~= 280 instrs/wave, the
//   largest VALU block (budget: ~880 VALU instrs/wave at VALUBusy 46%). cvt_pk does
//   2 converts/instr (RNE, bit-identical): 64 f2bf -> 32 cvt_pk + 32 lshr.
// Structural experiments R11-R15 all hit hardware walls (grid.sync cross-XCD flush;
// L2 atomic-op ceiling; L2 gather thrash when staging deviates from this regime).
// The dense sorted-tile staging + barrier-free 4-wave MFMA kernel stays verbatim.

typedef unsigned short ushort_t;
typedef __attribute__((ext_vector_type(8))) short     bf16x8;   // 8 bf16 = 4 VGPRs
typedef __attribute__((ext_vector_type(8))) unsigned short u16x8;
typedef __attribute__((ext_vector_type(4))) float     f32x4;

constexpr int D        = 64;
constexpr int TILE     = 64;     // edges per block (4 waves x 16 edges)
constexpr int BLOCK    = 256;
constexpr int NFRAG    = 32;     // 16 (W1) + 8 (W2) + 8 (W2@Wg) B-fragments
constexpr int SLAB_B   = 4352;   // per-wave slab: 16 rows x 272 B
constexpr int PAIR_STR = 136;    // pair row stride (bf16): 272 B
constexpr int H_STR    = 72;     // h row stride (bf16): 144 B
constexpr float LOG2E  = 1.4426950408889634f;

static __device__ __forceinline__ ushort_t f2bf(float f) {
    union { float f; unsigned int u; } v; v.f = f;
    const unsigned int r = v.u + 0x7FFFu + ((v.u >> 16) & 1u);   // RNE
    return (ushort_t)(r >> 16);
}

static __device__ __forceinline__ float fexp2(float x) {
    float r; asm("v_exp_f32 %0, %1" : "=v"(r) : "v"(x)); return r;
}
static __device__ __forceinline__ float frcp(float x) {
    float r; asm("v_rcp_f32 %0, %1" : "=v"(r) : "v"(x)); return r;
}
// two f32 -> packed bf16 pair (lo | hi<<16), RNE -- same usage as HK's P->bf16 path
static __device__ __forceinline__ unsigned cvt_pk_bf16(float lo, float hi) {
    unsigned r;
    asm("v_cvt_pk_bf16_f32 %0, %1, %2" : "=v"(r) : "v"(lo), "v"(hi));
    return r;
}

// ---- prep: pack + W2Wg + bg' + emb->bf16 + histogram + summed-zero, one dispatch ----
// Weight fragment layout (verified R3): frag f, lane l, elem j -> W[k][n],
// k = kc*32 + (l>>4)*8 + j, n = nt*16 + (l&15).
// f in [0,16): W1; [16,24): W2; [24,32): (W2@Wg)*log2e.

__global__ void prep_kernel(const float* __restrict__ W1, const float* __restrict__ W2,
                            const float* __restrict__ Wg,
                            const float* __restrict__ b2, const float* __restrict__ bg,
                            const float* __restrict__ emb, const int* __restrict__ ei,
                            ushort_t* __restrict__ wpack, float* __restrict__ bgp,
                            ushort_t* __restrict__ emb_bf, int* __restrict__ cnt,
                            float* __restrict__ summed,
                            int total_emb, int cvt_blocks, int e4blocks, int E) {
    const int bid = blockIdx.x;
    if (bid < 64) {                              // 64*256 == NFRAG*512: weight packing
        const int t = bid * 256 + threadIdx.x;
        const int f = t >> 9;
        const int l = (t >> 3) & 63;
        const int j = t & 7;
        const int k = ((f < 16) ? (f & 3) : ((f - 16) & 1)) * 32 + (l >> 4) * 8 + j;
        const int n = ((f < 16) ? (f >> 2) : (((f & 7)) >> 1)) * 16 + (l & 15);
        float v;
        if (f < 16)      v = W1[k * 64 + n];
        else if (f < 24) v = W2[k * 64 + n];
        else {                                   // (W2@Wg)[k][n] * log2(e)
            float s = 0.f;
            const float* wr = W2 + k * 64;
#pragma unroll 8
            for (int m = 0; m < 64; ++m) s += wr[m] * Wg[m * 64 + n];
            v = s * LOG2E;
        }
        wpack[t] = f2bf(v);
    } else if (bid < 64 + cvt_blocks) {          // node_emb -> bf16
        const int idx  = (bid - 64) * 256 + threadIdx.x;
        const int base = idx * 8;
        if (base < total_emb) {
            const float4 a = *(const float4*)(emb + base);
            const float4 b = *(const float4*)(emb + base + 4);
            u16x8 p;
            p[0]=f2bf(a.x); p[1]=f2bf(a.y); p[2]=f2bf(a.z); p[3]=f2bf(a.w);
            p[4]=f2bf(b.x); p[5]=f2bf(b.y); p[6]=f2bf(b.z); p[7]=f2bf(b.w);
            *(u16x8*)(emb_bf + base) = p;
        }
    } else if (bid == 64 + cvt_blocks) {         // bg' = (b2@Wg + bg) * log2(e)  (fp32)
        const int n = threadIdx.x;
        if (n < 64) {
            float s = bg[n];
#pragma unroll 8
            for (int m = 0; m < 64; ++m) s += b2[m] * Wg[m * 64 + n];
            bgp[n] = s * LOG2E;
        }
    } else if (bid < 65 + cvt_blocks + e4blocks) {   // edge histogram by src
        const int e = ((bid - 65 - cvt_blocks) * 256 + threadIdx.x) * 4;
        if (e + 3 < E) {
            const int4 v = *(const int4*)(ei + e);
            atomicAdd(&cnt[v.x], 1); atomicAdd(&cnt[v.y], 1);
            atomicAdd(&cnt[v.z], 1); atomicAdd(&cnt[v.w], 1);
        } else {
            for (int k = e; k < E; ++k) atomicAdd(&cnt[ei[k]], 1);
        }
    } else {                                     // zero summed (consumed 2 nodes later)
        const int idx  = (bid - 65 - cvt_blocks - e4blocks) * 256 + threadIdx.x;
        const int base = idx * 4;
        if (base < total_emb)
            *(float4*)(summed + base) = (float4){0.f, 0.f, 0.f, 0.f};
    }
}

// ---------------- scan: per-block exclusive offsets + block sums ----------

__global__ void scan_block(const int* __restrict__ cnt, int* __restrict__ off,
                           int* __restrict__ bsum, int N) {
    __shared__ int s[256];
    const int t = threadIdx.x, i = blockIdx.x * 256 + t;
    const int x = (i < N) ? cnt[i] : 0;
    s[t] = x; __syncthreads();
    for (int d = 1; d < 256; d <<= 1) {
        const int v = (t >= d) ? s[t - d] : 0;
        __syncthreads();
        s[t] += v;
        __syncthreads();
    }
    if (i < N) off[i] = s[t] - x;                 // block-local exclusive prefix
    if (t == 255) bsum[blockIdx.x] = s[255];
}

// scatter with inline bsum prefix (nb <= 256); off[] doubles as insertion cursor.
// Writes packed (src<<16)|dst per slot -- requires N < 65536.
__global__ void scatter_idx(const int* __restrict__ ei, int* __restrict__ off,
                            const int* __restrict__ bsum, unsigned* __restrict__ sorted,
                            int E, int nb) {
    __shared__ int pref[256];
    const int t = threadIdx.x;
    const int x = (t < nb) ? bsum[t] : 0;
    pref[t] = x; __syncthreads();
    for (int d = 1; d < 256; d <<= 1) {
        const int v = (t >= d) ? pref[t - d] : 0;
        __syncthreads();
        pref[t] += v;
        __syncthreads();
    }
    // pref[] inclusive prefix of bsum; exclusive for block b is pref[b-1] (0 if b==0)
    const int e = (blockIdx.x * blockDim.x + t) * 4;
    if (e + 3 < E) {
        const int4 v = *(const int4*)(ei + e);        // src
        const int4 d = *(const int4*)(ei + E + e);    // dst
        const int bx = v.x >> 8, by = v.y >> 8, bz = v.z >> 8, bw = v.w >> 8;
        sorted[(bx ? pref[bx - 1] : 0) + atomicAdd(&off[v.x], 1)] =
            ((unsigned)v.x << 16) | (unsigned)d.x;
        sorted[(by ? pref[by - 1] : 0) + atomicAdd(&off[v.y], 1)] =
            ((unsigned)v.y << 16) | (unsigned)d.y;
        sorted[(bz ? pref[bz - 1] : 0) + atomicAdd(&off[v.z], 1)] =
            ((unsigned)v.z << 16) | (unsigned)d.z;
        sorted[(bw ? pref[bw - 1] : 0) + atomicAdd(&off[v.w], 1)] =
            ((unsigned)v.w << 16) | (unsigned)d.w;
    } else {
        for (int k = e; k < E; ++k) {
            const int s = ei[k], b = s >> 8;
            sorted[(b ? pref[b - 1] : 0) + atomicAdd(&off[s], 1)] =
                ((unsigned)s << 16) | (unsigned)ei[E + k];
        }
    }
}

// ---------------- fused MFMA MLP + register segmented scatter (barrier-free) --------
// Wave w exclusively owns its 4352B slab + srcIds/rcS rows 16w..16w+15. All LDS
// dependencies are intra-wave (issue-order DS pipe + compiler lgkmcnt waits), so
// pair -> h reuse one slab with no __syncthreads. Gated values never touch LDS:
// segmented reduction via per-lane prefix sums + ballot boundary mask + scalar
// segment loop; cross-quad butterfly only at flush.

__global__ __launch_bounds__(BLOCK, 8)
void edge_mlp_mfma(const ushort_t* __restrict__ emb_bf,   // [N][64] bf16
                   const unsigned* __restrict__ sorted,   // packed (src<<16)|dst, sorted
                   const ushort_t* __restrict__ wpack,    // 32 packed B-frags
                   const float* __restrict__ b1, const float* __restrict__ b2,
                   const float* __restrict__ bgp,         // (b2@Wg + bg) * log2e
                   const int*   __restrict__ cnt,         // per-node edge counts
                   float* __restrict__ summed,            // [N][D] pre-zeroed
                   int E)
{
    __shared__ char  slab[4][SLAB_B];    // 17408 B: per-wave pair then h
    __shared__ int   srcIds[TILE];
    __shared__ float rcS[TILE];

    const int tid = threadIdx.x;

    // ---- stage: one packed 4B load -> two 128B row gathers into per-wave slab ----
    {
        const int e = tid >> 2, q4 = tid & 3;     // e: edge slot 0..63, q4: 16-elem quarter
        ushort_t* prow = (ushort_t*)&slab[e >> 4][(e & 15) * (PAIR_STR * 2)];
        const int ide = blockIdx.x * TILE + e;
        if (ide < E) {
            const unsigned p = sorted[ide];
            const int s  = (int)(p >> 16);
            const int dn = (int)(p & 0xFFFFu);
            if (q4 == 0) { srcIds[e] = s; rcS[e] = frcp(fmaxf((float)cnt[s], 1.0f)); }
            const ushort_t* sr = emb_bf + (size_t)s  * D + q4 * 16;
            const ushort_t* dr = emb_bf + (size_t)dn * D + q4 * 16;
            *(u16x8*)&prow[q4 * 16]          = *(const u16x8*)sr;
            *(u16x8*)&prow[q4 * 16 + 8]      = *(const u16x8*)(sr + 8);
            *(u16x8*)&prow[64 + q4 * 16]     = *(const u16x8*)dr;
            *(u16x8*)&prow[64 + q4 * 16 + 8] = *(const u16x8*)(dr + 8);
        } else {
            if (q4 == 0) { srcIds[e] = -1; rcS[e] = 1.0f; }
            const u16x8 z = {0,0,0,0,0,0,0,0};
            *(u16x8*)&prow[q4 * 16]          = z;
            *(u16x8*)&prow[q4 * 16 + 8]      = z;
            *(u16x8*)&prow[64 + q4 * 16]     = z;
            *(u16x8*)&prow[64 + q4 * 16 + 8] = z;
        }
    }

    const int w    = tid >> 6;           // wave id: owns slab[w] + rows 16w..16w+15
    const int ln   = tid & 63;
    const int quad = ln >> 4;
    const int cn   = ln & 15;
    ushort_t* pairW = (ushort_t*)slab[w];   // [16][136]
    ushort_t* hW    = (ushort_t*)slab[w];   // [16][72]  (overwrites pair after a1 reads)

    // ---- GEMM1: h = relu(pair @ W1 + b1), M=16 K=128 N=64 (kc-outer) ----
    f32x4 acc1[4];
#pragma unroll
    for (int nt = 0; nt < 4; ++nt) {
        const float b = b1[nt * 16 + cn];
        acc1[nt] = (f32x4){b, b, b, b};
    }
#pragma unroll
    for (int kc = 0; kc < 4; ++kc) {
        const bf16x8 a = *(const bf16x8*)&pairW[cn * PAIR_STR + kc * 32 + quad * 8];
#pragma unroll
        for (int nt = 0; nt < 4; ++nt) {
            const bf16x8 bf = *(const bf16x8*)(wpack + ((nt * 4 + kc) * 64 + ln) * 8);
            acc1[nt] = __builtin_amdgcn_mfma_f32_16x16x32_bf16(a, bf, acc1[nt], 0, 0, 0);
        }
    }
    // h-store: v_cvt_pk_bf16_f32 does 2 RNE converts/instr (rows 2r,2r+1 share one pk;
    // LDS targets stay b16 stores -- rows are H_STR apart, not contiguous)
#pragma unroll
    for (int nt = 0; nt < 4; ++nt)
#pragma unroll
        for (int rp = 0; rp < 2; ++rp) {
            const unsigned pk = cvt_pk_bf16(fmaxf(acc1[nt][2 * rp],     0.f),
                                            fmaxf(acc1[nt][2 * rp + 1], 0.f));
            hW[(quad * 4 + 2 * rp)     * H_STR + nt * 16 + cn] = (ushort_t)(pk & 0xFFFFu);
            hW[(quad * 4 + 2 * rp + 1) * H_STR + nt * 16 + cn] = (ushort_t)(pk >> 16);
        }

    // ---- GEMM2+3 fused (kc-outer): interaction = h@W2+b2 ; gate_pre = h@(W2Wg*log2e)+bg' ----
    f32x4 acc2[4], accg[4];
#pragma unroll
    for (int nt = 0; nt < 4; ++nt) {
        const float b  = b2 [nt * 16 + cn];
        const float bG = bgp[nt * 16 + cn];
        acc2[nt] = (f32x4){b, b, b, b};
        accg[nt] = (f32x4){bG, bG, bG, bG};
    }
#pragma unroll
    for (int kc = 0; kc < 2; ++kc) {
        const bf16x8 a = *(const bf16x8*)&hW[cn * H_STR + kc * 32 + quad * 8];
#pragma unroll
        for (int nt = 0; nt < 4; ++nt) {
            const bf16x8 bf2 = *(const bf16x8*)(wpack + ((16 + nt * 2 + kc) * 64 + ln) * 8);
            const bf16x8 bfg = *(const bf16x8*)(wpack + ((24 + nt * 2 + kc) * 64 + ln) * 8);
            acc2[nt] = __builtin_amdgcn_mfma_f32_16x16x32_bf16(a, bf2, acc2[nt], 0, 0, 0);
            accg[nt] = __builtin_amdgcn_mfma_f32_16x16x32_bf16(a, bfg, accg[nt], 0, 0, 0);
        }
    }

    // ---- gated = interaction * sigmoid(gate_pre), folded into per-lane PREFIX sums ----
    // accg is pre-scaled by log2(e): sigmoid(x) = rcp(1 + 2^-x_hat). rcp/exp2 approx
    // (~1e-7 rel) is far below bf16 noise. P[nt][r] = sum of gated rows 4q..4q+r.
    float P[4][4];
#pragma unroll
    for (int nt = 0; nt < 4; ++nt) {
#pragma unroll
        for (int r = 0; r < 4; ++r) {
            const float ex = fexp2(-accg[nt][r]);
            P[nt][r] = acc2[nt][r] * frcp(1.0f + ex);
        }
        P[nt][1] += P[nt][0];
        P[nt][2] += P[nt][1];
        P[nt][3] += P[nt][2];
    }

    // ---- segmented scatter: ballot boundary mask + scalar segment loop ----
    {
        const int   rbase  = 16 * w;
        const int   myRow  = ln & 15;
        const int   mySrc  = srcIds[rbase + myRow];
        const float myRc   = rcS[rbase + myRow];
        const int   prevSrc = srcIds[rbase + ((myRow + 15) & 15)];   // wraps; bit0 forced
        unsigned bmask = ((unsigned)__ballot(mySrc != prevSrc) & 0xFFFFu) | 1u;
        const int q4r = 4 * quad;
        while (bmask) {
            const int a = __builtin_ctz(bmask);
            bmask &= (bmask - 1u);
            const int b = bmask ? __builtin_ctz(bmask) : 16;
            const int sseg = __builtin_amdgcn_readlane(mySrc, a);
            if (sseg >= 0) {
                // lane's row range for this segment: [a,b) ∩ [4q,4q+4), as prefix diff
                const int lo  = a - q4r, hi = b - q4r;
                const int clo = lo < 0 ? 0 : (lo > 4 ? 4 : lo);
                const int chi = hi < 0 ? 0 : (hi > 4 ? 4 : hi);
                const bool ge1 = chi > 1, ge2 = chi > 2, ge3 = chi > 3;
                const bool l0 = clo > 0, l1 = clo > 1, l2 = clo > 2;
                const bool valid = chi > clo;
                float t[4];
#pragma unroll
                for (int nt = 0; nt < 4; ++nt) {
                    const float sh = ge2 ? (ge3 ? P[nt][3] : P[nt][2])
                                         : (ge1 ? P[nt][1] : P[nt][0]);
                    const float sl = l1 ? (l2 ? P[nt][2] : P[nt][1])
                                        : (l0 ? P[nt][0] : 0.f);
                    t[nt] = valid ? sh - sl : 0.f;
                }
                t[0] += __shfl_xor(t[0], 16); t[0] += __shfl_xor(t[0], 32);
                t[1] += __shfl_xor(t[1], 16); t[1] += __shfl_xor(t[1], 32);
                t[2] += __shfl_xor(t[2], 16); t[2] += __shfl_xor(t[2], 32);
                t[3] += __shfl_xor(t[3], 16); t[3] += __shfl_xor(t[3], 32);
                const float tot = (quad < 2) ? (quad == 0 ? t[0] : t[1])
                                             : (quad == 2 ? t[2] : t[3]);
                const float rc = __uint_as_float(
                    __builtin_amdgcn_readlane(__float_as_uint(myRc), a));
                unsafeAtomicAdd(&summed[(size_t)sseg * D + ln], tot * rc);
            }
        }
    }
}

extern "C" void kernel_launch(void* const* d_in, const int* in_sizes, int n_in,
                              void* d_out, int out_size, void* d_ws, size_t ws_size,
                              hipStream_t stream) {
    const float* node_emb   = (const float*)d_in[0];
    const int*   edge_index = (const int*)d_in[1];
    const float* W1 = (const float*)d_in[2];
    const float* b1 = (const float*)d_in[3];
    const float* W2 = (const float*)d_in[4];
    const float* b2 = (const float*)d_in[5];
    const float* Wg = (const float*)d_in[6];
    const float* bg = (const float*)d_in[7];

    const int N = in_sizes[0] / D;
    const int E = in_sizes[1] / 2;
    const int total_emb = N * D;

    // ws layout == R5..R10's proven extent (10,034,048 B for N=50000, E=800000):
    // cnt[N] | off[N] | bsum[256] | sorted[E u32] | bgp[64 f32] | wpack[16K bf16] | emb_bf
    int* cnt    = (int*)d_ws;
    int* off    = cnt + N;
    int* bsum   = off + N;
    unsigned* sorted = (unsigned*)(bsum + 256);
    float* bgp  = (float*)(sorted + E);
    ushort_t* wpack  = (ushort_t*)(bgp + 64);
    ushort_t* emb_bf = wpack + NFRAG * 512;

    float* summed = (float*)d_out;

    hipMemsetAsync(cnt, 0, sizeof(int) * (size_t)N, stream);   // must precede prep's hist

    const int cvt_blocks = (total_emb / 8 + 255) / 256;
    const int e4blocks   = ((E + 3) / 4 + 255) / 256;
    const int zblocks    = (total_emb / 4 + 255) / 256;
    prep_kernel<<<64 + cvt_blocks + 1 + e4blocks + zblocks, 256, 0, stream>>>(
        W1, W2, Wg, b2, bg, node_emb, edge_index,
        wpack, bgp, emb_bf, cnt, summed, total_emb, cvt_blocks, e4blocks, E);

    const int nblocks = (N + 255) / 256;   // 196 (must be <= 256 for inline prefix)
    scan_block <<<nblocks, 256, 0, stream>>>(cnt, off, bsum, N);
    scatter_idx<<<e4blocks, 256, 0, stream>>>(edge_index, off, bsum, sorted, E, nblocks);

    const int ntiles = (E + TILE - 1) / TILE;
    edge_mlp_mfma<<<ntiles, BLOCK, 0, stream>>>(emb_bf, sorted, wpack,
                                                b1, b2, bgp, cnt, summed, E);
}